// Round 8
// baseline (381.412 us; speedup 1.0000x reference)
//
#include <hip/hip_runtime.h>
#include <math.h>

#define NPTS 4096
#define BLK 128
#define V 64
#define NPROJ 256
#define NBATCH 32

// R14 (resubmit — R7 bench was an infra failure, container never acquired):
// R13 with amdgpu_waves_per_eu(2, 3) — the single remaining fix for the
// AGPR-shuttle tax.
// Decoded allocator behavior (two data points):
//   R12 (no max):   target = LDS-implied 5/EU -> 102 regs = 56 VGPR + 46 AGPR
//   R13 (max = 4):  target = 512/4 = 128 regs = 64 VGPR + 64 AGPR (exactly)
// => the allocator aims at waves_per_eu MAX and splits V/A to fit it. v[64]
// never fit in the arch-VGPR half, so every cmpex on an AGPR-resident element
// paid v_accvgpr_read/write (VALU-busy 208us vs ~108us op floor).
// max = 3 -> 512/3 ~= 170-reg budget -> the ~95-110 live values allocate as
// pure VGPR, zero shuttles. Occupancy: reg-bound 12 waves/CU (37.5%) vs 41%
// — small loss, large per-wave instruction-count win.
// Everything else byte-identical to verified R13 (absmax 0.0):
//   LDS-free shfl-bitonic sort, layout A (element idx = lane*64 + reg);
//   merges 2..64 in-reg; merge m>=128: rev_shfl<(m-1)>>6>,
//   stage_shfl<j>>6> j=m/4..64, stages<32,1> in-reg.
//   Cross-lane keep = compare-select ((q<v)!=hi ? q : v): v_cmp + s_xor_b64
//   (SALU pipe) + v_cndmask = 2 VALU/elem.
//   LDS = one 16 KiB publish buffer (wave 1 sorted y -> wave 0 fused diff).

__device__ __forceinline__ void cmpex_asc(float& a, float& b) {
    const float lo = fminf(a, b), hi = fmaxf(a, b);
    a = lo; b = hi;
}

template<int JB, int JL>
__device__ __forceinline__ void stages(float* v) {
#pragma unroll
    for (int r = 0; r < V; ++r)
        if ((r & JB) == 0) cmpex_asc(v[r], v[r | JB]);
    if constexpr (JB > JL) stages<(JB >> 1), JL>(v);
}

template<int MASK>
__device__ __forceinline__ void rev_inreg(float* v) {
    constexpr int S = (MASK + 1) >> 1;
#pragma unroll
    for (int r = 0; r < V; ++r) {
        if ((r & S) == 0) {
            const float a = v[r], b = v[r ^ MASK];
            v[r] = fminf(a, b);
            v[r ^ MASK] = fmaxf(a, b);
        }
    }
}

// Keep-side select: hi lanes keep max, lo lanes keep min, of (mine, q).
// ((q < mine) != hi) ? q : mine  ==  hi ? max : min   (ties keep mine).
// Lowers to v_cmp + s_xor_b64 (hi is a loop-invariant lane-mask) + v_cndmask.
__device__ __forceinline__ float keep(float mine, float q, bool hi) {
    return ((q < mine) != hi) ? q : mine;
}

// Reversal across thread-pair (xor XM), registers reversed (r <-> 63-r).
// Element (t, r) exchanges with (t^XM, 63-r); hi lanes keep max.
template<int XM>
__device__ __forceinline__ void rev_shfl(float* v, bool hi) {
#pragma unroll
    for (int r = 0; r < 32; ++r) {
        const float pa = __shfl_xor(v[63 - r], XM, 64);
        const float pb = __shfl_xor(v[r], XM, 64);
        v[r]      = keep(v[r],      pa, hi);
        v[63 - r] = keep(v[63 - r], pb, hi);
    }
}
// Same-register cross-thread stage (xor XM).
template<int XM>
__device__ __forceinline__ void stage_shfl(float* v, bool hi) {
#pragma unroll
    for (int r = 0; r < V; ++r) {
        const float q = __shfl_xor(v[r], XM, 64);
        v[r] = keep(v[r], q, hi);
    }
}

// Natural (own-slot) publish write, float4-slot = (t<<4)|(c^t15)
// (bank-spreading XOR placement: 2 lanes/bank per instr = conflict-free).
__device__ __forceinline__ void write_own(float* s, const float* v, int t, int t15) {
    float4* s4 = (float4*)s;
#pragma unroll
    for (int c = 0; c < 16; ++c)
        s4[(t << 4) | (c ^ t15)] =
            make_float4(v[4*c], v[4*c+1], v[4*c+2], v[4*c+3]);
}

__device__ __forceinline__ void load_project(const float* base, float* v,
                                             float p0, float p1, float p2) {
    const float4* b4 = (const float4*)base;
#pragma unroll
    for (int g = 0; g < 16; ++g) {
        float4 a = b4[g * 3 + 0], c = b4[g * 3 + 1], d = b4[g * 3 + 2];
        v[4*g+0] = a.x * p0 + a.y * p1 + a.z * p2;
        v[4*g+1] = a.w * p0 + c.x * p1 + c.y * p2;
        v[4*g+2] = c.z * p0 + c.w * p1 + d.x * p2;
        v[4*g+3] = d.y * p0 + d.z * p1 + d.w * p2;
    }
}

// Full ascending sort of 4096 floats held as v[64] per thread, layout A
// (element idx = t*64 + r). Pure in-register + cross-lane; no LDS.
__device__ __forceinline__ void sort4096(float* v, int t) {
    const bool hi1  = (t & 1) != 0;
    const bool hi2  = (t & 2) != 0;
    const bool hi4  = (t & 4) != 0;
    const bool hi8  = (t & 8) != 0;
    const bool hi16 = (t & 16) != 0;
    const bool hi32 = (t & 32) != 0;

    // merges 2..64: fully in-register
    rev_inreg<1>(v);
    rev_inreg<3>(v);  stages<1, 1>(v);
    rev_inreg<7>(v);  stages<2, 1>(v);
    rev_inreg<15>(v); stages<4, 1>(v);
    rev_inreg<31>(v); stages<8, 1>(v);
    rev_inreg<63>(v); stages<16, 1>(v);

    // merge 128
    rev_shfl<1>(v, hi1);
    stages<32, 1>(v);

    // merge 256
    rev_shfl<3>(v, hi2);
    stage_shfl<2>(v, hi2);
    stage_shfl<1>(v, hi1);
    stages<32, 1>(v);

    // merge 512
    rev_shfl<7>(v, hi4);
    stage_shfl<2>(v, hi2);
    stage_shfl<1>(v, hi1);
    stages<32, 1>(v);

    // merge 1024
    rev_shfl<15>(v, hi8);
    stage_shfl<4>(v, hi4);
    stage_shfl<2>(v, hi2);
    stage_shfl<1>(v, hi1);
    stages<32, 1>(v);

    // merge 2048
    rev_shfl<31>(v, hi16);
    stage_shfl<8>(v, hi8);
    stage_shfl<4>(v, hi4);
    stage_shfl<2>(v, hi2);
    stage_shfl<1>(v, hi1);
    stages<32, 1>(v);

    // merge 4096
    rev_shfl<63>(v, hi32);
    stage_shfl<16>(v, hi16);
    stage_shfl<8>(v, hi8);
    stage_shfl<4>(v, hi4);
    stage_shfl<2>(v, hi2);
    stage_shfl<1>(v, hi1);
    stages<32, 1>(v);
}

__global__ __launch_bounds__(BLK)
__attribute__((amdgpu_waves_per_eu(2, 3)))
void swd_kernel(
    const float* __restrict__ x, const float* __restrict__ y,
    const float* __restrict__ theta, const float* __restrict__ rot,
    float* __restrict__ per_batch) {
    __shared__ float buf[NPTS];   // 16 KiB — publish buffer only

    const int t = threadIdx.x & 63;       // wave lane
    const int wave = threadIdx.x >> 6;    // 0: x, 1: y
    const int p = blockIdx.x;
    const int b = blockIdx.y;

    const float t0 = theta[p * 3 + 0], t1 = theta[p * 3 + 1], t2 = theta[p * 3 + 2];
    const float* R = rot + b * 9;
    const float p0 = t0 * R[0] + t1 * R[3] + t2 * R[6];
    const float p1 = t0 * R[1] + t1 * R[4] + t2 * R[7];
    const float p2 = t0 * R[2] + t1 * R[5] + t2 * R[8];

    const float* src = wave ? y : x;

    // Each wave sorts its own array, completely barrier- and LDS-free.
    float v[V];
    load_project(src + (size_t)b * NPTS * 3 + (size_t)t * V * 3, v, p0, p1, p2);
    sort4096(v, t);

    const int t15 = t & 15;
    // Wave 1 publishes sorted y; wave 0 then diffs.
    if (wave == 1) write_own(buf, v, t, t15);
    __syncthreads();

    if (wave == 0) {
        // Fused read+diff: w never materializes (epilogue pressure ~v[64]+8).
        const float4* s4 = (const float4*)buf;
        float s = 0.0f;
#pragma unroll
        for (int c = 0; c < 16; ++c) {
            const float4 f = s4[(t << 4) | (c ^ t15)];
            const float d0 = v[4*c+0] - f.x;
            const float d1 = v[4*c+1] - f.y;
            const float d2 = v[4*c+2] - f.z;
            const float d3 = v[4*c+3] - f.w;
            s += d0 * d0 + d1 * d1 + d2 * d2 + d3 * d3;
        }
        for (int off = 32; off > 0; off >>= 1) s += __shfl_down(s, off, 64);
        if (t == 0) atomicAdd(&per_batch[b], s);
    }
}

__global__ void finalize_kernel(const float* __restrict__ per_batch, float* __restrict__ out) {
    const int t = threadIdx.x;  // 64 threads
    float v = (t < NBATCH) ? sqrtf(per_batch[t] * (1.0f / (float)NPROJ)) : 0.0f;
    for (int off = 32; off > 0; off >>= 1) v += __shfl_down(v, off, 64);
    if (t == 0) out[0] = v * (1.0f / (float)NBATCH);
}

extern "C" void kernel_launch(void* const* d_in, const int* in_sizes, int n_in,
                              void* d_out, int out_size, void* d_ws, size_t ws_size,
                              hipStream_t stream) {
    const float* x = (const float*)d_in[0];
    const float* y = (const float*)d_in[1];
    const float* theta = (const float*)d_in[2];
    const float* rot = (const float*)d_in[3];
    float* per_batch = (float*)d_ws;
    float* out = (float*)d_out;

    hipMemsetAsync(per_batch, 0, NBATCH * sizeof(float), stream);

    dim3 grid(NPROJ, NBATCH);
    swd_kernel<<<grid, BLK, 0, stream>>>(x, y, theta, rot, per_batch);

    finalize_kernel<<<1, 64, 0, stream>>>(per_batch, out);
}